// Round 1
// baseline (515.813 us; speedup 1.0000x reference)
//
#include <hip/hip_runtime.h>

// ---------------------------------------------------------------------------
// MQA forward: out = OutProj( MHA( x·Wq^T, x·Wk^T, x·Wv^T ) )
// B=2, L=2048, D=2048, H=16, dh=128 (MQA: K/V shared across heads)
// Strategy: cast everything to bf16 in ws, run bf16 MFMA GEMMs (m97-style
// 128^2 tile, global_load_lds staging), flash-style attention, fp32 epilogue.
// ---------------------------------------------------------------------------

typedef __attribute__((ext_vector_type(8))) short bf16x8;
typedef __attribute__((ext_vector_type(4))) short short4v;
typedef __attribute__((ext_vector_type(4))) float f32x4;

__device__ __forceinline__ unsigned short f2bf(float f) {
  unsigned int u = __builtin_bit_cast(unsigned int, f);
  u += 0x7fffu + ((u >> 16) & 1u);           // RNE (finite inputs only)
  return (unsigned short)(u >> 16);
}

typedef __attribute__((address_space(1))) void gvoid_t;
typedef __attribute__((address_space(3))) void lvoid_t;

__device__ __forceinline__ void gll16(const void* g, void* l) {
  // async global->LDS, 16B per lane; LDS dest must be wave-uniform base.
  __builtin_amdgcn_global_load_lds((gvoid_t*)g, (lvoid_t*)l, 16, 0, 0);
}

// ---------------------------------------------------------------------------
// fp32 -> bf16 cast, vectorized 4-wide
// ---------------------------------------------------------------------------
__global__ void cast_bf16_kernel(const float* __restrict__ in,
                                 unsigned short* __restrict__ out, int n4) {
  int i = blockIdx.x * blockDim.x + threadIdx.x;
  int stride = gridDim.x * blockDim.x;
  for (; i < n4; i += stride) {
    float4 f = reinterpret_cast<const float4*>(in)[i];
    short4v o;
    o.x = (short)f2bf(f.x);
    o.y = (short)f2bf(f.y);
    o.z = (short)f2bf(f.z);
    o.w = (short)f2bf(f.w);
    reinterpret_cast<short4v*>(out)[i] = o;
  }
}

// ---------------------------------------------------------------------------
// GEMM: C[M,N] = A[M,K] · B[N,K]^T   (bf16 in, fp32 acc)
// 128x128 tile, BK=32, 4 waves (each 64x64 = 4x4 fragments of 16x16x32).
// MODE 0: bf16 store C[m*N+n] * scale
// MODE 1: bf16 transposed store C[n*M+m] * scale   (used to build V^T)
// MODE 2: fp32 store C[m*N+n] + bias[n]
// ---------------------------------------------------------------------------
template <int MODE>
__global__ __launch_bounds__(256) void gemm_bt(
    const unsigned short* __restrict__ A, const unsigned short* __restrict__ B,
    void* __restrict__ Cout, int M, int N, int K, float scale,
    const float* __restrict__ bias) {
  __shared__ unsigned short As[128 * 32] __attribute__((aligned(16)));
  __shared__ unsigned short Bs[128 * 32] __attribute__((aligned(16)));

  const int tid = threadIdx.x;
  const int lane = tid & 63;
  const int wave = tid >> 6;
  const int lr = lane & 15;
  const int lg = lane >> 4;
  const int bm = blockIdx.x * 128;
  const int bn = blockIdx.y * 128;
  const int wrow = (wave >> 1) * 64;
  const int wcol = (wave & 1) * 64;

  f32x4 acc[4][4] = {};

  const int c0 = tid;        // staging chunk ids (16B each)
  const int c1 = tid + 256;

  for (int k0 = 0; k0 < K; k0 += 32) {
    __syncthreads();  // protect LDS from previous iteration's readers
    // stage A,B tiles: [128 rows][32 cols] bf16 row-major, 8KB each
    gll16(A + (size_t)(bm + (c0 >> 2)) * K + k0 + (c0 & 3) * 8,
          (char*)As + wave * 1024);
    gll16(A + (size_t)(bm + (c1 >> 2)) * K + k0 + (c1 & 3) * 8,
          (char*)As + 4096 + wave * 1024);
    gll16(B + (size_t)(bn + (c0 >> 2)) * K + k0 + (c0 & 3) * 8,
          (char*)Bs + wave * 1024);
    gll16(B + (size_t)(bn + (c1 >> 2)) * K + k0 + (c1 & 3) * 8,
          (char*)Bs + 4096 + wave * 1024);
    __syncthreads();  // compiler emits vmcnt(0) drain before s_barrier

    bf16x8 af[4], bfr[4];
#pragma unroll
    for (int mi = 0; mi < 4; mi++)
      af[mi] = *(const bf16x8*)&As[(wrow + mi * 16 + lr) * 32 + 8 * lg];
#pragma unroll
    for (int nj = 0; nj < 4; nj++)
      bfr[nj] = *(const bf16x8*)&Bs[(wcol + nj * 16 + lr) * 32 + 8 * lg];
#pragma unroll
    for (int mi = 0; mi < 4; mi++)
#pragma unroll
      for (int nj = 0; nj < 4; nj++)
        acc[mi][nj] = __builtin_amdgcn_mfma_f32_16x16x32_bf16(
            af[mi], bfr[nj], acc[mi][nj], 0, 0, 0);
  }

  // epilogue: D layout col = lane&15, row = (lane>>4)*4 + r
#pragma unroll
  for (int mi = 0; mi < 4; mi++)
#pragma unroll
    for (int nj = 0; nj < 4; nj++) {
      const int row = bm + wrow + mi * 16 + lg * 4;
      const int col = bn + wcol + nj * 16 + lr;
#pragma unroll
      for (int r = 0; r < 4; r++) {
        float v = acc[mi][nj][r] * scale;
        if constexpr (MODE == 0) {
          ((unsigned short*)Cout)[(size_t)(row + r) * N + col] = f2bf(v);
        } else if constexpr (MODE == 1) {
          ((unsigned short*)Cout)[(size_t)col * M + (row + r)] = f2bf(v);
        } else {
          ((float*)Cout)[(size_t)(row + r) * N + col] = v + bias[col];
        }
      }
    }
}

// ---------------------------------------------------------------------------
// Flash-style MQA attention.
// Q: [B*L, 2048] bf16 (pre-scaled by 1/sqrt(dh)), head h at cols h*128..+128
// K: [B*L, 128] bf16 ; VT: [128, B*L] bf16 (V transposed)
// O: [B*L, 2048] bf16 (attn output, head-concatenated)
// Block: 256 threads = 4 waves; each wave owns 32 q-rows of one (b,h).
// grid: (L/128, B*H)
// ---------------------------------------------------------------------------
__global__ __launch_bounds__(256) void mqa_attn(
    const unsigned short* __restrict__ Q, const unsigned short* __restrict__ Kb,
    const unsigned short* __restrict__ VT, unsigned short* __restrict__ Ob) {
  __shared__ unsigned short ldsP[4][16][32] __attribute__((aligned(16)));

  const int lane = threadIdx.x & 63;
  const int wave = threadIdx.x >> 6;
  const int lr = lane & 15;
  const int lg = lane >> 4;
  const int bh = blockIdx.y;
  const int b = bh >> 4;
  const int h = bh & 15;
  const int q0 = blockIdx.x * 128 + wave * 32;

  const unsigned short* Qb = Q + ((size_t)(b * 2048 + q0)) * 2048 + h * 128;
  const unsigned short* Kbase = Kb + (size_t)b * 2048 * 128;
  const unsigned short* VTb = VT + (size_t)b * 2048;

  // Q fragments: A[m=q][k=d], lane: m=lr, k=8*lg+i
  bf16x8 qf[2][4];
#pragma unroll
  for (int mi = 0; mi < 2; mi++)
#pragma unroll
    for (int ks = 0; ks < 4; ks++)
      qf[mi][ks] =
          *(const bf16x8*)&Qb[(size_t)(mi * 16 + lr) * 2048 + ks * 32 + 8 * lg];

  f32x4 oacc[2][8] = {};
  float mrun[2][4], lrun[2][4];
#pragma unroll
  for (int mi = 0; mi < 2; mi++)
#pragma unroll
    for (int r = 0; r < 4; r++) {
      mrun[mi][r] = -1e30f;
      lrun[mi][r] = 0.0f;
    }

  for (int kv0 = 0; kv0 < 2048; kv0 += 32) {
    // K fragments: B[k=d][n=kv], lane: n=lr -> kv row, k=8*lg+i contiguous in d
    bf16x8 kf[2][4];
#pragma unroll
    for (int nj = 0; nj < 2; nj++)
#pragma unroll
      for (int ks = 0; ks < 4; ks++)
        kf[nj][ks] = *(const bf16x8*)&Kbase[(size_t)(kv0 + nj * 16 + lr) * 128 +
                                            ks * 32 + 8 * lg];
    // V^T fragments: B[k=kv][n=d], lane: n=lr -> d row of VT, k=8*lg+i in kv
    bf16x8 vf[8];
#pragma unroll
    for (int dt = 0; dt < 8; dt++)
      vf[dt] =
          *(const bf16x8*)&VTb[(size_t)(dt * 16 + lr) * 4096 + kv0 + 8 * lg];

    // S = Q · K^T  (rows q = lg*4+r, cols kv = kv0 + nj*16 + lr)
    f32x4 s[2][2];
#pragma unroll
    for (int mi = 0; mi < 2; mi++)
#pragma unroll
      for (int nj = 0; nj < 2; nj++) {
        f32x4 z = {0.f, 0.f, 0.f, 0.f};
#pragma unroll
        for (int ks = 0; ks < 4; ks++)
          z = __builtin_amdgcn_mfma_f32_16x16x32_bf16(qf[mi][ks], kf[nj][ks], z,
                                                      0, 0, 0);
        s[mi][nj] = z;
      }

#pragma unroll
    for (int mi = 0; mi < 2; mi++) {
      float p0[4], p1[4];
#pragma unroll
      for (int r = 0; r < 4; r++) {
        // row-max over 32 kv: 2 local cols + 16-lane butterfly
        float t = fmaxf(s[mi][0][r], s[mi][1][r]);
        t = fmaxf(t, __shfl_xor(t, 1));
        t = fmaxf(t, __shfl_xor(t, 2));
        t = fmaxf(t, __shfl_xor(t, 4));
        t = fmaxf(t, __shfl_xor(t, 8));
        float mnew = fmaxf(mrun[mi][r], t);
        float sc = __expf(mrun[mi][r] - mnew);
        mrun[mi][r] = mnew;
        p0[r] = __expf(s[mi][0][r] - mnew);
        p1[r] = __expf(s[mi][1][r] - mnew);
        float ps = p0[r] + p1[r];
        ps += __shfl_xor(ps, 1);
        ps += __shfl_xor(ps, 2);
        ps += __shfl_xor(ps, 4);
        ps += __shfl_xor(ps, 8);
        lrun[mi][r] = lrun[mi][r] * sc + ps;
#pragma unroll
        for (int dt = 0; dt < 8; dt++) oacc[mi][dt][r] *= sc;
      }
      // repack P (S-layout) -> A-frag layout via per-wave LDS tile
#pragma unroll
      for (int r = 0; r < 4; r++) {
        ldsP[wave][lg * 4 + r][lr] = f2bf(p0[r]);
        ldsP[wave][lg * 4 + r][16 + lr] = f2bf(p1[r]);
      }
      bf16x8 pa = *(const bf16x8*)&ldsP[wave][lr][8 * lg];
#pragma unroll
      for (int dt = 0; dt < 8; dt++)
        oacc[mi][dt] = __builtin_amdgcn_mfma_f32_16x16x32_bf16(pa, vf[dt],
                                                               oacc[mi][dt], 0,
                                                               0, 0);
    }
  }

  // normalize + store (attn_out[b,l, h*128 + d])
#pragma unroll
  for (int mi = 0; mi < 2; mi++)
#pragma unroll
    for (int r = 0; r < 4; r++) {
      float inv = 1.0f / lrun[mi][r];
      size_t row = (size_t)(b * 2048 + q0 + mi * 16 + lg * 4 + r);
#pragma unroll
      for (int dt = 0; dt < 8; dt++)
        Ob[row * 2048 + h * 128 + dt * 16 + lr] =
            f2bf(oacc[mi][dt][r] * inv);
    }
}

// ---------------------------------------------------------------------------
extern "C" void kernel_launch(void* const* d_in, const int* in_sizes, int n_in,
                              void* d_out, int out_size, void* d_ws,
                              size_t ws_size, hipStream_t stream) {
  const float* x = (const float*)d_in[0];
  const float* Wq = (const float*)d_in[1];
  const float* Wk = (const float*)d_in[2];
  const float* Wv = (const float*)d_in[3];
  const float* Wo = (const float*)d_in[4];
  const float* bo = (const float*)d_in[5];

  const int Bb = 2, Lq = 2048, D = 2048, DH = 128;
  const int M = Bb * Lq;  // 4096

  char* ws = (char*)d_ws;
  size_t off = 0;
  auto alloc = [&](size_t bytes) {
    void* p = ws + off;
    off += (bytes + 255) & ~size_t(255);
    return p;
  };
  unsigned short* x_bf = (unsigned short*)alloc((size_t)M * D * 2);
  unsigned short* Wq_bf = (unsigned short*)alloc((size_t)D * D * 2);
  unsigned short* Wk_bf = (unsigned short*)alloc((size_t)DH * D * 2);
  unsigned short* Wv_bf = (unsigned short*)alloc((size_t)DH * D * 2);
  unsigned short* Wo_bf = (unsigned short*)alloc((size_t)D * D * 2);
  unsigned short* Qbuf = (unsigned short*)alloc((size_t)M * D * 2);
  unsigned short* Kbuf = (unsigned short*)alloc((size_t)M * DH * 2);
  unsigned short* VTbuf = (unsigned short*)alloc((size_t)DH * M * 2);
  unsigned short* AObuf = (unsigned short*)alloc((size_t)M * D * 2);
  // total ws use ~70 MB

  auto cast = [&](const float* in, unsigned short* outp, int n) {
    int n4 = n >> 2;
    int grid = (n4 + 255) / 256;
    if (grid > 2048) grid = 2048;
    cast_bf16_kernel<<<grid, 256, 0, stream>>>(in, outp, n4);
  };
  cast(x, x_bf, M * D);
  cast(Wq, Wq_bf, D * D);
  cast(Wk, Wk_bf, DH * D);
  cast(Wv, Wv_bf, DH * D);
  cast(Wo, Wo_bf, D * D);

  // Q = x·Wq^T, scaled by 1/sqrt(dh) so attention logits need no scaling
  gemm_bt<0><<<dim3(M / 128, D / 128), 256, 0, stream>>>(
      x_bf, Wq_bf, Qbuf, M, D, D, 0.08838834764831845f, nullptr);
  // K = x·Wk^T
  gemm_bt<0><<<dim3(M / 128, DH / 128), 256, 0, stream>>>(
      x_bf, Wk_bf, Kbuf, M, DH, D, 1.0f, nullptr);
  // V^T = (x·Wv^T)^T stored [128, M]
  gemm_bt<1><<<dim3(M / 128, DH / 128), 256, 0, stream>>>(
      x_bf, Wv_bf, VTbuf, M, DH, D, 1.0f, nullptr);
  // attention
  mqa_attn<<<dim3(Lq / 128, Bb * 16), 256, 0, stream>>>(Qbuf, Kbuf, VTbuf,
                                                        AObuf);
  // out = AO·Wo^T + bo  (fp32 output)
  gemm_bt<2><<<dim3(M / 128, D / 128), 256, 0, stream>>>(
      AObuf, Wo_bf, d_out, M, D, D, 1.0f, bo);
}